// Round 6
// baseline (427.817 us; speedup 1.0000x reference)
//
#include <hip/hip_runtime.h>
#include <math.h>

#define NUM_EMB 1024
#define EMB_DIM 256
#define NROWS   65536
#define NTHREADS 256
#define EPSF 1.5e-3f
#define LLCAP 800

// out layout (float32, concatenated):
#define OFF_IDX  16777216
#define OFF_VQ   16842752

// ws layout (bytes):
#define WS_C2    0         // float[1024]  ||e_k||^2 sequential fp32 (verified R3)
#define WS_HIST  4096      // int[1024]
#define WS_LOSS  8192      // float
#define WS_ETF   8448      // float[1024][256]  emb^T fp32
#define WS_ETB   1057024   // ushort[1024][256] emb^T bf16

typedef __attribute__((ext_vector_type(8))) short bf16x8;
typedef __attribute__((ext_vector_type(4))) float f32x4;

__device__ __forceinline__ unsigned short f2bf(float x) {
  unsigned u = __float_as_uint(x);
  unsigned r = (u + 0x7FFFu + ((u >> 16) & 1u)) >> 16;
  return (unsigned short)r;
}

// exact numpy-fp32 dot: strict sequential-d fmaf chain [verified R3]
__device__ __forceinline__ float exact_dist(const float* __restrict__ zr,
                                            const float* __restrict__ er,
                                            float r2v, float c2v) {
  float s = 0.f;
  #pragma unroll 8
  for (int d4 = 0; d4 < 64; ++d4) {
    float4 a = *(const float4*)(zr + d4 * 4);
    float4 b = *(const float4*)(er + d4 * 4);
    s = fmaf(a.x, b.x, s); s = fmaf(a.y, b.y, s);
    s = fmaf(a.z, b.z, s); s = fmaf(a.w, b.w, s);
  }
  return __fsub_rn(__fadd_rn(r2v, c2v), __fmul_rn(2.0f, s));
}

// transpose emb [256][1024] -> embTf fp32 [1024][256] + embTbf bf16
__global__ __launch_bounds__(NTHREADS) void vq_tr(
    const float* __restrict__ emb, float* __restrict__ embTf,
    unsigned short* __restrict__ embTbf) {
  __shared__ float t[64][65];
  const int kt = blockIdx.x & 15, dt = blockIdx.x >> 4;
  const int tid = threadIdx.x;
  #pragma unroll
  for (int it = 0; it < 16; ++it) {
    int i = tid + it * NTHREADS, r = i >> 6, c = i & 63;
    t[r][c] = emb[(dt * 64 + r) * NUM_EMB + kt * 64 + c];
  }
  __syncthreads();
  #pragma unroll
  for (int it = 0; it < 16; ++it) {
    int i = tid + it * NTHREADS, r = i >> 6, c = i & 63;
    float v = t[c][r];
    embTf[(kt * 64 + r) * EMB_DIM + dt * 64 + c] = v;
    embTbf[(kt * 64 + r) * EMB_DIM + dt * 64 + c] = f2bf(v);
  }
}

// c2[k] = sequential-d fp32 sum of fl(e[d,k]^2)  [same values+order as R3]
__global__ __launch_bounds__(NTHREADS) void vq_prep2(
    const float* __restrict__ embTf, float* __restrict__ cvec,
    int* __restrict__ hist, float* __restrict__ loss) {
  int k = blockIdx.x * NTHREADS + threadIdx.x;
  const float4* row = (const float4*)(embTf + (size_t)k * EMB_DIM);
  float s = 0.f;
  #pragma unroll 8
  for (int i = 0; i < 64; ++i) {
    float4 v = row[i];
    s = __fadd_rn(s, __fmul_rn(v.x, v.x));
    s = __fadd_rn(s, __fmul_rn(v.y, v.y));
    s = __fadd_rn(s, __fmul_rn(v.z, v.z));
    s = __fadd_rn(s, __fmul_rn(v.w, v.w));
  }
  cvec[k] = s;
  hist[k] = 0;
  if (k == 0) *loss = 0.f;
}

// Fused: bf16-MFMA sweep (prefetched B from global) -> in-block exact refine
// -> in-block epilogue (gather, ST write, loss, hist). Block = 64 rows.
__global__ __launch_bounds__(NTHREADS, 3) void vq_fused(
    const float* __restrict__ z, const float* __restrict__ embTf,
    const unsigned short* __restrict__ embTbf, const float* __restrict__ cvec,
    float* __restrict__ out, int* __restrict__ hist, float* __restrict__ loss) {
  __shared__ unsigned short zc[64][264];    // A bf16 [m][k], 528B rows (2-way-free)
  __shared__ float c2s[NUM_EMB];            // ||e||^2 + 1.0 (positive)
  __shared__ int rowminb[64];               // running bf16 row-min (float bits)
  __shared__ float r2s[64];                 // exact numpy-pairwise ||z_n||^2
  __shared__ int slotd[64];                 // exact min dist bits
  __shared__ int slotk[64];                 // min k among bit-equal dists
  __shared__ unsigned int llist[4][LLCAP];  // per-wave candidates (rowl<<10|k)
  __shared__ int lcnt[4];
  __shared__ int ovf;
  __shared__ float wsum[4];

  const int tid = threadIdx.x;
  const int wave = tid >> 6, lane = tid & 63;
  const int quad = lane >> 4, l15 = lane & 15;
  const int n0 = blockIdx.x * 64;
  const float* zblk = z + (size_t)n0 * EMB_DIM;

  // ---- prologue ----
  #pragma unroll
  for (int it = 0; it < 16; ++it) {
    int g = tid + it * NTHREADS, row = g >> 6, f4 = g & 63;
    float4 v = *(const float4*)(zblk + row * EMB_DIM + f4 * 4);
    ushort4 b; b.x = f2bf(v.x); b.y = f2bf(v.y); b.z = f2bf(v.z); b.w = f2bf(v.w);
    *(ushort4*)(&zc[row][f4 * 4]) = b;
  }
  // r2: numpy pairwise tree [verified R3], combined via in-wave shuffles.
  {
    const int prow = tid >> 2, pm = tid & 3;   // 4 consecutive lanes per row
    float racc[2][2] = {{0.f, 0.f}, {0.f, 0.f}};
    for (int dc = 0; dc < 8; ++dc) {
      const int half = dc >> 2;
      #pragma unroll
      for (int q = 0; q < 4; ++q)
        #pragma unroll
        for (int jj = 0; jj < 2; ++jj) {
          float v = zblk[prow * EMB_DIM + dc * 32 + q * 8 + pm * 2 + jj];
          racc[half][jj] = __fadd_rn(racc[half][jj], __fmul_rn(v, v));
        }
    }
    float t0 = __fadd_rn(racc[0][0], racc[0][1]);  // (r2pm + r2pm+1), half 0
    float t1 = __fadd_rn(racc[1][0], racc[1][1]);
    const int lb = lane & ~3;
    float a0 = __shfl(t0, lb + 0), a1 = __shfl(t0, lb + 1);
    float a2 = __shfl(t0, lb + 2), a3 = __shfl(t0, lb + 3);
    float b0 = __shfl(t1, lb + 0), b1 = __shfl(t1, lb + 1);
    float b2 = __shfl(t1, lb + 2), b3 = __shfl(t1, lb + 3);
    if (pm == 0) {
      float h0 = __fadd_rn(__fadd_rn(a0, a1), __fadd_rn(a2, a3));
      float h1 = __fadd_rn(__fadd_rn(b0, b1), __fadd_rn(b2, b3));
      r2s[prow] = __fadd_rn(h0, h1);
    }
  }
  for (int i = tid; i < NUM_EMB; i += NTHREADS) c2s[i] = cvec[i] + 1.0f;
  if (tid < 64) {
    rowminb[tid] = 0x7F000000;
    slotd[tid] = 0x7F000000;
    slotk[tid] = 1 << 20;
  }
  if (tid < 4) lcnt[tid] = 0;
  if (tid == 0) ovf = 0;
  __syncthreads();                           // barrier #1

  // ---- sweep: wave owns codes [wave*256, wave*256+256), flattened (jt,kc) ----
  const int cbase = wave * 256;
  f32x4 acc[4][4];
  bf16x8 bvn[4];
  #pragma unroll
  for (int ct = 0; ct < 4; ++ct)
    bvn[ct] = *(const bf16x8*)(embTbf + (size_t)(cbase + ct * 16 + l15) * EMB_DIM + quad * 8);
  #pragma unroll
  for (int rt = 0; rt < 4; ++rt)
    #pragma unroll
    for (int ct = 0; ct < 4; ++ct)
      acc[rt][ct] = (f32x4){0.f, 0.f, 0.f, 0.f};

  #pragma unroll
  for (int it = 0; it < 32; ++it) {
    const int jt = it >> 3, kc = it & 7;
    const int c0 = cbase + jt * 64;
    bf16x8 bv[4];
    #pragma unroll
    for (int ct = 0; ct < 4; ++ct) bv[ct] = bvn[ct];
    if (it < 31) {
      const int njt = (it + 1) >> 3, nkc = (it + 1) & 7;
      const int nc0 = cbase + njt * 64;
      #pragma unroll
      for (int ct = 0; ct < 4; ++ct)
        bvn[ct] = *(const bf16x8*)(embTbf + (size_t)(nc0 + ct * 16 + l15) * EMB_DIM
                                   + nkc * 32 + quad * 8);
    }
    bf16x8 av[4];
    #pragma unroll
    for (int rt = 0; rt < 4; ++rt)
      av[rt] = *(const bf16x8*)(&zc[rt * 16 + l15][kc * 32 + quad * 8]);
    #pragma unroll
    for (int rt = 0; rt < 4; ++rt)
      #pragma unroll
      for (int ct = 0; ct < 4; ++ct)
        acc[rt][ct] = __builtin_amdgcn_mfma_f32_16x16x32_bf16(av[rt], bv[ct], acc[rt][ct], 0, 0, 0);

    if (kc == 7) {
      // tile epilogue: dist' = 1 + c2 - 2s; shared row-min; capture
      #pragma unroll
      for (int rt = 0; rt < 4; ++rt)
        #pragma unroll
        for (int reg = 0; reg < 4; ++reg) {
          const int rowl = rt * 16 + quad * 4 + reg;
          float d[4];
          #pragma unroll
          for (int ct = 0; ct < 4; ++ct)
            d[ct] = fmaf(-2.f, acc[rt][ct][reg], c2s[c0 + ct * 16 + l15]);
          float m = fminf(fminf(d[0], d[1]), fminf(d[2], d[3]));
          #pragma unroll
          for (int off = 1; off < 16; off <<= 1)
            m = fminf(m, __shfl_xor(m, off));
          if (l15 == 0) atomicMin(&rowminb[rowl], __float_as_int(m));
          float thr = __int_as_float(rowminb[rowl]) + EPSF;
          if (fminf(fminf(d[0], d[1]), fminf(d[2], d[3])) <= thr) {
            #pragma unroll
            for (int ct = 0; ct < 4; ++ct) {
              if (d[ct] <= thr) {
                int id = atomicAdd(&lcnt[wave], 1);
                if (id < LLCAP)
                  llist[wave][id] = ((unsigned)rowl << 10) | (unsigned)(c0 + ct * 16 + l15);
                else ovf = 1;
              }
            }
          }
          #pragma unroll
          for (int ct = 0; ct < 4; ++ct)
            acc[rt][ct][reg] = 0.f;          // reset for next jt
        }
    }
  }
  __syncthreads();                           // barrier #2: lists & mins final

  // ---- exact refine (two-phase 32-bit LDS argmin; numpy first-index rule) ----
  if (!ovf) {
    for (int w = 0; w < 4; ++w) {
      int cnt = lcnt[w]; if (cnt > LLCAP) cnt = LLCAP;
      for (int i = tid; i < cnt; i += NTHREADS) {
        unsigned e = llist[w][i];
        int rowl = (int)(e >> 10), k = (int)(e & 1023);
        float dist = exact_dist(zblk + rowl * EMB_DIM,
                                embTf + (size_t)k * EMB_DIM, r2s[rowl], cvec[k]);
        atomicMin(&slotd[rowl], __float_as_int(dist));
      }
    }
    __syncthreads();
    for (int w = 0; w < 4; ++w) {
      int cnt = lcnt[w]; if (cnt > LLCAP) cnt = LLCAP;
      for (int i = tid; i < cnt; i += NTHREADS) {
        unsigned e = llist[w][i];
        int rowl = (int)(e >> 10), k = (int)(e & 1023);
        float dist = exact_dist(zblk + rowl * EMB_DIM,
                                embTf + (size_t)k * EMB_DIM, r2s[rowl], cvec[k]);
        if (__float_as_int(dist) == slotd[rowl]) atomicMin(&slotk[rowl], k);
      }
    }
  } else {
    // fallback: exact scan of all 64x1024 pairs (never expected)
    const int rowl = tid >> 2, k0 = (tid & 3) * 256;
    for (int k = k0; k < k0 + 256; ++k) {
      float dist = exact_dist(zblk + rowl * EMB_DIM,
                              embTf + (size_t)k * EMB_DIM, r2s[rowl], cvec[k]);
      atomicMin(&slotd[rowl], __float_as_int(dist));
    }
    __syncthreads();
    for (int k = k0; k < k0 + 256; ++k) {
      float dist = exact_dist(zblk + rowl * EMB_DIM,
                              embTf + (size_t)k * EMB_DIM, r2s[rowl], cvec[k]);
      if (__float_as_int(dist) == slotd[rowl]) atomicMin(&slotk[rowl], k);
    }
  }
  __syncthreads();                           // barrier #3: slotk final

  // ---- epilogue: idx, hist, gather, ST write, loss ----
  if (tid < 64) {
    int k = slotk[tid];
    out[OFF_IDX + n0 + tid] = (float)k;
    atomicAdd(&hist[k], 1);
  }
  float sumsq = 0.f;
  #pragma unroll
  for (int it = 0; it < 16; ++it) {
    int g = tid + it * NTHREADS;
    int row = g >> 6;
    int d = (g & 63) * 4;
    int k = slotk[row];
    float4 zv = *(const float4*)(zblk + row * EMB_DIM + d);
    float4 q = *(const float4*)(embTf + (size_t)k * EMB_DIM + d);
    float4 df;
    df.x = q.x - zv.x; df.y = q.y - zv.y; df.z = q.z - zv.z; df.w = q.w - zv.w;
    sumsq = fmaf(df.x, df.x, sumsq);
    sumsq = fmaf(df.y, df.y, sumsq);
    sumsq = fmaf(df.z, df.z, sumsq);
    sumsq = fmaf(df.w, df.w, sumsq);
    *(float4*)(out + (size_t)(n0 + row) * EMB_DIM + d) = q;
  }
  #pragma unroll
  for (int off = 32; off > 0; off >>= 1) sumsq += __shfl_down(sumsq, off);
  if (lane == 0) wsum[wave] = sumsq;
  __syncthreads();
  if (tid == 0) atomicAdd(loss, wsum[0] + wsum[1] + wsum[2] + wsum[3]);
}

__global__ __launch_bounds__(NTHREADS) void vq_finalize(
    const int* __restrict__ hist, const float* __restrict__ loss,
    float* __restrict__ out) {
  __shared__ float ws[4];
  int tid = threadIdx.x;
  float s = 0.f;
  for (int k = tid; k < NUM_EMB; k += NTHREADS) {
    float p = (float)hist[k] * (1.0f / 65536.0f);
    s += p * logf(p + 1e-10f);
  }
  #pragma unroll
  for (int off = 32; off > 0; off >>= 1) s += __shfl_down(s, off);
  if ((tid & 63) == 0) ws[tid >> 6] = s;
  __syncthreads();
  if (tid == 0) {
    float tot = ws[0] + ws[1] + ws[2] + ws[3];
    float vq = *loss * (1.0f / 16777216.0f);
    out[OFF_VQ + 0] = vq;
    out[OFF_VQ + 1] = 0.25f * vq;
    out[OFF_VQ + 2] = expf(-tot);
  }
}

extern "C" void kernel_launch(void* const* d_in, const int* in_sizes, int n_in,
                              void* d_out, int out_size, void* d_ws, size_t ws_size,
                              hipStream_t stream) {
  const float* z   = (const float*)d_in[0];
  const float* emb = (const float*)d_in[1];
  float* out = (float*)d_out;
  char* ws = (char*)d_ws;
  float* cvec   = (float*)(ws + WS_C2);
  int*   hist   = (int*)(ws + WS_HIST);
  float* loss   = (float*)(ws + WS_LOSS);
  float* embTf  = (float*)(ws + WS_ETF);
  unsigned short* embTbf = (unsigned short*)(ws + WS_ETB);

  vq_tr<<<64, NTHREADS, 0, stream>>>(emb, embTf, embTbf);
  vq_prep2<<<4, NTHREADS, 0, stream>>>(embTf, cvec, hist, loss);
  vq_fused<<<NROWS / 64, NTHREADS, 0, stream>>>(z, embTf, embTbf, cvec, out, hist, loss);
  vq_finalize<<<1, NTHREADS, 0, stream>>>(hist, loss, out);
}